// Round 5
// baseline (97.172 us; speedup 1.0000x reference)
//
#include <hip/hip_runtime.h>

#define NUM_EMB 1024
#define EDIM 64
#define HW 4096      // 64*64 spatial
#define CHW 262144   // 64 ch * 4096
#define NPOS 65536   // 16 * 4096 positions
#define NOUT 4194304 // output elements (excl. loss scalar)

typedef __attribute__((ext_vector_type(8))) short short8;   // 8 bf16 = 4 VGPRs
typedef __attribute__((ext_vector_type(4))) float f32x4;

__device__ inline short f32_to_bf16_rne(float f) {
    unsigned u = __float_as_uint(f);
    unsigned r = (u + 0x7fffu + ((u >> 16) & 1u)) >> 16;
    return (short)r;
}

// Prep: codebook -> bf16(-e) swizzled B-fragments + biased half-norms + zero
// loss. Storing NEGATED codes lets the MFMA produce score = h - x.e directly
// (acc initialized to h), killing the per-candidate v_sub in the hot loop.
// B-frag (16x16x32): lane=(n&15)|(quad<<4) holds B[n][chunk*32+quad*8+j], j=0..7.
__global__ void vq_prep_kernel(const float* __restrict__ emb,
                               short* __restrict__ bsw,
                               float* __restrict__ hnb,
                               float* __restrict__ loss_out) {
    const int gid = blockIdx.x * 256 + threadIdx.x;   // 0..16383
    if (gid == 0) *loss_out = 0.0f;
    const int k  = gid >> 4;          // code id
    const int c0 = (gid & 15) * 4;    // channel group base
    float4 v = *(const float4*)(emb + k * EDIM + c0);
    float s = v.x * v.x + v.y * v.y + v.z * v.z + v.w * v.w;
#pragma unroll
    for (int m = 1; m < 16; m <<= 1) s += __shfl_xor(s, m, 64);
    if (c0 == 0) hnb[k] = 0.5f * s + 0.25f;           // bias -> scores positive

    const int T = k >> 4, nl = k & 15;
    const int chunk = c0 >> 5, quad = (c0 >> 3) & 3, j = c0 & 7;
    const int lane  = nl | (quad << 4);
    union { short s4[4]; uint2 u2; } pk;
    pk.s4[0] = f32_to_bf16_rne(-v.x);                 // NEGATED
    pk.s4[1] = f32_to_bf16_rne(-v.y);
    pk.s4[2] = f32_to_bf16_rne(-v.z);
    pk.s4[3] = f32_to_bf16_rne(-v.w);
    *(uint2*)(bsw + ((T * 2 + chunk) * 64 + lane) * 8 + j) = pk.u2;
}

// Main: block = 64 positions, 4 waves; all waves hold the same 4 M-tiles,
// wave w scans codebook quarter w (16 tiles). k-loop is register
// double-buffered: tile T+1's B-fragments + h are loaded while tile T
// computes, so the vmcnt wait for a tile lands one full iteration after its
// issue (cross-iteration latency hiding the compiler won't do on its own).
// Packed-uint argmin: u = (bits(score) & ~0x3FF) | code_id; scores biased
// positive so uint order == float order; low bits = first-index tie-break.
__global__ __launch_bounds__(256, 4) void vq_mfma_kernel(
        const float* __restrict__ inp,
        const float* __restrict__ emb,
        const short* __restrict__ bsw,
        const float* __restrict__ hnb,
        float* __restrict__ out,
        float* __restrict__ loss_out) {
    __shared__ unsigned s_red[4][64];
    __shared__ int      s_idx[64];
    __shared__ float    s_wsum[4];

    const int tid    = threadIdx.x;
    const int w      = tid >> 6;        // wave id = codebook quarter
    const int lane   = tid & 63;
    const int lanelo = lane & 15;
    const int quad   = lane >> 4;
    const int pb     = blockIdx.x * 64;

    // ---- A fragments: 4 M-tiles x 2 K-chunks. A[m=lane&15][k=quad*8+j]. ----
    short8 a[4][2];
#pragma unroll
    for (int t = 0; t < 4; ++t) {
        const int p = pb + t * 16 + lanelo;
        const float* xp = inp + (p >> 12) * CHW + (p & 4095);
#pragma unroll
        for (int chunk = 0; chunk < 2; ++chunk)
#pragma unroll
            for (int j = 0; j < 8; ++j) {
                int c = chunk * 32 + quad * 8 + j;
                a[t][chunk][j] = f32_to_bf16_rne(xp[c * HW]);
            }
    }

    unsigned best[4][4];
#pragma unroll
    for (int t = 0; t < 4; ++t)
#pragma unroll
        for (int r = 0; r < 4; ++r) best[t][r] = 0xFFFFFFFFu;

    // ---- k-loop: 16 tiles of 16 codes, register double-buffered ----
    int kn = w * 256 + lanelo;                        // current tile's code id
    const short* bp = bsw + (size_t)(w * 16) * 1024;  // 1024 shorts per tile
    short8 b0c = *(const short8*)(bp + lane * 8);
    short8 b1c = *(const short8*)(bp + 512 + lane * 8);
    float  hc  = hnb[kn];

#pragma unroll 1
    for (int T = 0; T < 16; ++T) {
        // prefetch tile T+1 (clamped: last iteration redundantly reloads)
        const short* bpn = (T < 15) ? (bp + 1024) : bp;
        const int    knn = (T < 15) ? (kn + 16) : kn;
        short8 b0n = *(const short8*)(bpn + lane * 8);
        short8 b1n = *(const short8*)(bpn + 512 + lane * 8);
        float  hn_ = hnb[knn];

        // score = h - x.e  (B holds -e; acc initialized to h)
        f32x4 acc[4];
#pragma unroll
        for (int t = 0; t < 4; ++t) acc[t] = (f32x4){hc, hc, hc, hc};
#pragma unroll
        for (int t = 0; t < 4; ++t) {
            acc[t] = __builtin_amdgcn_mfma_f32_16x16x32_bf16(a[t][0], b0c, acc[t], 0, 0, 0);
            acc[t] = __builtin_amdgcn_mfma_f32_16x16x32_bf16(a[t][1], b1c, acc[t], 0, 0, 0);
        }
#pragma unroll
        for (int t = 0; t < 4; ++t)
#pragma unroll
            for (int r = 0; r < 4; ++r) {
                unsigned u = (__float_as_uint(acc[t][r]) & ~1023u) | (unsigned)kn;
                if (u < best[t][r]) best[t][r] = u;
            }
        b0c = b0n; b1c = b1n; hc = hn_; kn = knn; bp = bpn;
    }

    // ---- cross-lane min over the 16 codes (lanelo bits), stash per wave ----
#pragma unroll
    for (int t = 0; t < 4; ++t)
#pragma unroll
        for (int r = 0; r < 4; ++r) {
            unsigned b = best[t][r];
#pragma unroll
            for (int m = 1; m < 16; m <<= 1) {
                unsigned o = __shfl_xor(b, m, 64);
                if (o < b) b = o;
            }
            if (lanelo == 0)
                s_red[w][t * 16 + quad * 4 + r] = b;  // C/D row = quad*4+r
        }
    __syncthreads();

    if (tid < 64) {                                   // merge 4 codebook quarters
        unsigned u0 = s_red[0][tid], u1 = s_red[1][tid];
        unsigned u2 = s_red[2][tid], u3 = s_red[3][tid];
        unsigned m01 = u0 < u1 ? u0 : u1;
        unsigned m23 = u2 < u3 ? u2 : u3;
        s_idx[tid] = (int)((m01 < m23 ? m01 : m23) & 1023u);
    }
    __syncthreads();

    // ---- epilogue: gather exact fp32 code rows, write [B,C,H,W], loss ----
    const int pos = tid & 63;
    const int c0  = (tid >> 6) * 16;
    const int p   = pb + pos;
    const int b   = p >> 12, hw = p & 4095;
    const int myk = s_idx[pos];
    const float4* er4 = reinterpret_cast<const float4*>(emb + myk * EDIM + c0);
    const float*  xr   = inp + b * CHW + hw;
    float*        orow = out + b * CHW + hw;
    float part = 0.0f;
#pragma unroll
    for (int i4 = 0; i4 < 4; ++i4) {
        float4 q4 = er4[i4];
        int c = c0 + i4 * 4;
        float d;
        d = q4.x - xr[(c + 0) * HW]; part = fmaf(d, d, part); orow[(c + 0) * HW] = q4.x;
        d = q4.y - xr[(c + 1) * HW]; part = fmaf(d, d, part); orow[(c + 1) * HW] = q4.y;
        d = q4.z - xr[(c + 2) * HW]; part = fmaf(d, d, part); orow[(c + 2) * HW] = q4.z;
        d = q4.w - xr[(c + 3) * HW]; part = fmaf(d, d, part); orow[(c + 3) * HW] = q4.w;
    }

#pragma unroll
    for (int off = 32; off > 0; off >>= 1)
        part += __shfl_down(part, off, 64);
    if (lane == 0) s_wsum[w] = part;
    __syncthreads();
    if (tid == 0) {
        float s = (s_wsum[0] + s_wsum[1]) + (s_wsum[2] + s_wsum[3]);
        atomicAdd(loss_out, s * (1.25f / (float)NOUT));
    }
}

extern "C" void kernel_launch(void* const* d_in, const int* in_sizes, int n_in,
                              void* d_out, int out_size, void* d_ws, size_t ws_size,
                              hipStream_t stream) {
    const float* inp = (const float*)d_in[0];    // [16,64,64,64] fp32
    const float* emb = (const float*)d_in[1];    // [1024,64] fp32
    float* out  = (float*)d_out;                 // 4194304 quantized + 1 loss
    float* loss = out + NOUT;

    short* bsw = (short*)d_ws;                           // 128 KiB bf16 -e swizzled
    float* hnb = (float*)((char*)d_ws + 131072);         // 4 KiB biased half-norms

    vq_prep_kernel<<<64, 256, 0, stream>>>(emb, bsw, hnb, loss);
    vq_mfma_kernel<<<NPOS / 64, 256, 0, stream>>>(inp, emb, bsw, hnb, out, loss);
}

// Round 6
// 95.677 us; speedup vs baseline: 1.0156x; 1.0156x over previous
//
#include <hip/hip_runtime.h>

#define NUM_EMB 1024
#define EDIM 64
#define HW 4096      // 64*64 spatial
#define CHW 262144   // 64 ch * 4096
#define NPOS 65536   // 16 * 4096 positions
#define NOUT 4194304 // output elements (excl. loss scalar)
#define XP 72        // LDS x-tile pitch in shorts (16B-aligned rows: 144 B)

typedef __attribute__((ext_vector_type(8))) short short8;   // 8 bf16 = 4 VGPRs
typedef __attribute__((ext_vector_type(4))) float f32x4;

__device__ inline short f32_to_bf16_rne(float f) {
    unsigned u = __float_as_uint(f);
    unsigned r = (u + 0x7fffu + ((u >> 16) & 1u)) >> 16;
    return (short)r;
}
__device__ inline float bf16s_to_f32(short s) {
    return __uint_as_float(((unsigned)(unsigned short)s) << 16);
}

// Prep: codebook -> bf16(-e) swizzled B-fragments + biased half-norms + zero
// loss. Negated codes let MFMA produce score = h - x.e directly (acc init h).
// B-frag (16x16x32): lane=(n&15)|(quad<<4) holds B[n][chunk*32+quad*8+j], j=0..7.
__global__ void vq_prep_kernel(const float* __restrict__ emb,
                               short* __restrict__ bsw,
                               float* __restrict__ hnb,
                               float* __restrict__ loss_out) {
    const int gid = blockIdx.x * 256 + threadIdx.x;   // 0..16383
    if (gid == 0) *loss_out = 0.0f;
    const int k  = gid >> 4;          // code id
    const int c0 = (gid & 15) * 4;    // channel group base
    float4 v = *(const float4*)(emb + k * EDIM + c0);
    float s = v.x * v.x + v.y * v.y + v.z * v.z + v.w * v.w;
#pragma unroll
    for (int m = 1; m < 16; m <<= 1) s += __shfl_xor(s, m, 64);
    if (c0 == 0) hnb[k] = 0.5f * s + 0.25f;           // bias -> scores positive

    const int T = k >> 4, nl = k & 15;
    const int chunk = c0 >> 5, quad = (c0 >> 3) & 3, j = c0 & 7;
    const int lane  = nl | (quad << 4);
    union { short s4[4]; uint2 u2; } pk;
    pk.s4[0] = f32_to_bf16_rne(-v.x);                 // NEGATED
    pk.s4[1] = f32_to_bf16_rne(-v.y);
    pk.s4[2] = f32_to_bf16_rne(-v.z);
    pk.s4[3] = f32_to_bf16_rne(-v.w);
    *(uint2*)(bsw + ((T * 2 + chunk) * 64 + lane) * 8 + j) = pk.u2;
}

// Main: block = 64 positions, 4 waves. Input tile staged through LDS with
// coalesced float4 loads (no per-wave redundant strided scalar loads); waves
// read A-fragments via ds_read_b128. Wave w scans codebook quarter w.
// Packed-uint argmin; vectorized dwordx4 epilogue; loss from LDS bf16 x.
__global__ __launch_bounds__(256, 4) void vq_mfma_kernel(
        const float* __restrict__ inp,
        const float* __restrict__ emb,
        const short* __restrict__ bsw,
        const float* __restrict__ hnb,
        float* __restrict__ out,
        float* __restrict__ loss_out) {
    __shared__ short    xs[64 * XP];     // 9216 B: x tile, [pos][ch] bf16
    __shared__ unsigned s_red[4][64];
    __shared__ int      s_idx[64];
    __shared__ float    s_wsum[4];

    const int tid    = threadIdx.x;
    const int w      = tid >> 6;        // wave id = codebook quarter
    const int lane   = tid & 63;
    const int lanelo = lane & 15;
    const int quad   = lane >> 4;
    const int pb     = blockIdx.x * 64;
    const int b      = pb >> 12;        // 64 | 4096 -> whole block same batch
    const int hw0    = pb & 4095;
    const float* xbase = inp + b * CHW + hw0;

    // ---- stage input tile: 1024 float4 loads, fully coalesced ----
#pragma unroll
    for (int g = 0; g < 4; ++g) {
        const int i  = tid + 256 * g;     // 0..1023
        const int c  = i >> 4;            // channel
        const int p4 = i & 15;            // position quad
        float4 v = *(const float4*)(xbase + c * HW + p4 * 4);
        xs[(p4 * 4 + 0) * XP + c] = f32_to_bf16_rne(v.x);
        xs[(p4 * 4 + 1) * XP + c] = f32_to_bf16_rne(v.y);
        xs[(p4 * 4 + 2) * XP + c] = f32_to_bf16_rne(v.z);
        xs[(p4 * 4 + 3) * XP + c] = f32_to_bf16_rne(v.w);
    }
    __syncthreads();

    // ---- A fragments from LDS: 4 M-tiles x 2 K-chunks, ds_read_b128 ----
    // A[m=lane&15][k=quad*8+j]; row m at xs + m*XP (144 B, 16B-aligned).
    short8 a[4][2];
#pragma unroll
    for (int t = 0; t < 4; ++t)
#pragma unroll
        for (int chunk = 0; chunk < 2; ++chunk)
            a[t][chunk] = *(const short8*)&xs[(t * 16 + lanelo) * XP + chunk * 32 + quad * 8];

    unsigned best[4][4];
#pragma unroll
    for (int t = 0; t < 4; ++t)
#pragma unroll
        for (int r = 0; r < 4; ++r) best[t][r] = 0xFFFFFFFFu;

    // ---- k-loop: 16 tiles of 16 codes (this wave's quarter) ----
    int kn = w * 256 + lanelo;
    const short* bp = bsw + (size_t)(w * 16) * 1024;  // 1024 shorts per tile
#pragma unroll 2
    for (int T = 0; T < 16; ++T) {
        const short8 b0 = *(const short8*)(bp + lane * 8);
        const short8 b1 = *(const short8*)(bp + 512 + lane * 8);
        const float  h  = hnb[kn];
        f32x4 acc[4];
#pragma unroll
        for (int t = 0; t < 4; ++t) acc[t] = (f32x4){h, h, h, h};
#pragma unroll
        for (int t = 0; t < 4; ++t) {
            acc[t] = __builtin_amdgcn_mfma_f32_16x16x32_bf16(a[t][0], b0, acc[t], 0, 0, 0);
            acc[t] = __builtin_amdgcn_mfma_f32_16x16x32_bf16(a[t][1], b1, acc[t], 0, 0, 0);
        }
#pragma unroll
        for (int t = 0; t < 4; ++t)
#pragma unroll
            for (int r = 0; r < 4; ++r) {
                unsigned u = (__float_as_uint(acc[t][r]) & ~1023u) | (unsigned)kn;
                if (u < best[t][r]) best[t][r] = u;
            }
        kn += 16;
        bp += 1024;
    }

    // ---- cross-lane min over the 16 codes (lanelo bits), stash per wave ----
#pragma unroll
    for (int t = 0; t < 4; ++t)
#pragma unroll
        for (int r = 0; r < 4; ++r) {
            unsigned v = best[t][r];
#pragma unroll
            for (int m = 1; m < 16; m <<= 1) {
                unsigned o = __shfl_xor(v, m, 64);
                if (o < v) v = o;
            }
            if (lanelo == 0)
                s_red[w][t * 16 + quad * 4 + r] = v;  // C/D row = quad*4+r
        }
    __syncthreads();

    if (tid < 64) {                                   // merge 4 codebook quarters
        unsigned u0 = s_red[0][tid], u1 = s_red[1][tid];
        unsigned u2 = s_red[2][tid], u3 = s_red[3][tid];
        unsigned m01 = u0 < u1 ? u0 : u1;
        unsigned m23 = u2 < u3 ? u2 : u3;
        s_idx[tid] = (int)((m01 < m23 ? m01 : m23) & 1023u);
    }
    __syncthreads();

    // ---- epilogue: thread = (channel, 4 consecutive positions) ----
    // dwordx4 store per group; exact fp32 emb gather; loss vs LDS bf16 x.
    float part = 0.0f;
    float* obase = out + b * CHW + hw0;
#pragma unroll
    for (int g = 0; g < 4; ++g) {
        const int c  = (tid >> 4) + 16 * g;
        const int p0 = (tid & 15) * 4;
        float4 qv;
        qv.x = emb[s_idx[p0 + 0] * EDIM + c];
        qv.y = emb[s_idx[p0 + 1] * EDIM + c];
        qv.z = emb[s_idx[p0 + 2] * EDIM + c];
        qv.w = emb[s_idx[p0 + 3] * EDIM + c];
        float d;
        d = qv.x - bf16s_to_f32(xs[(p0 + 0) * XP + c]); part = fmaf(d, d, part);
        d = qv.y - bf16s_to_f32(xs[(p0 + 1) * XP + c]); part = fmaf(d, d, part);
        d = qv.z - bf16s_to_f32(xs[(p0 + 2) * XP + c]); part = fmaf(d, d, part);
        d = qv.w - bf16s_to_f32(xs[(p0 + 3) * XP + c]); part = fmaf(d, d, part);
        *(float4*)(obase + c * HW + p0) = qv;
    }

#pragma unroll
    for (int off = 32; off > 0; off >>= 1)
        part += __shfl_down(part, off, 64);
    if (lane == 0) s_wsum[w] = part;
    __syncthreads();
    if (tid == 0) {
        float s = (s_wsum[0] + s_wsum[1]) + (s_wsum[2] + s_wsum[3]);
        atomicAdd(loss_out, s * (1.25f / (float)NOUT));
    }
}

extern "C" void kernel_launch(void* const* d_in, const int* in_sizes, int n_in,
                              void* d_out, int out_size, void* d_ws, size_t ws_size,
                              hipStream_t stream) {
    const float* inp = (const float*)d_in[0];    // [16,64,64,64] fp32
    const float* emb = (const float*)d_in[1];    // [1024,64] fp32
    float* out  = (float*)d_out;                 // 4194304 quantized + 1 loss
    float* loss = out + NOUT;

    short* bsw = (short*)d_ws;                           // 128 KiB bf16 -e swizzled
    float* hnb = (float*)((char*)d_ws + 131072);         // 4 KiB biased half-norms

    vq_prep_kernel<<<64, 256, 0, stream>>>(emb, bsw, hnb, loss);
    vq_mfma_kernel<<<NPOS / 64, 256, 0, stream>>>(inp, emb, bsw, hnb, out, loss);
}